// Round 13
// baseline (258.165 us; speedup 1.0000x reference)
//
#include <hip/hip_runtime.h>
#include <hip/hip_bf16.h>
#include <hip/hip_cooperative_groups.h>

namespace cg = cooperative_groups;

#define F_   512
#define FF_  (512 * 512)
#define C_   128

typedef __attribute__((ext_vector_type(4))) float f32x4;
typedef __attribute__((ext_vector_type(8))) short s16x8;
typedef __attribute__((ext_vector_type(4))) unsigned short u16x4;

__device__ __forceinline__ unsigned short f2bf(float f) {
    union { __hip_bfloat16 h; unsigned short u; } c;
    c.h = __float2bfloat16(f);
    return c.u;
}

__device__ __forceinline__ s16x8 pack8(f32x4 lo, f32x4 hi) {
    s16x8 r;
    r[0] = (short)f2bf(lo[0]); r[1] = (short)f2bf(lo[1]);
    r[2] = (short)f2bf(lo[2]); r[3] = (short)f2bf(lo[3]);
    r[4] = (short)f2bf(hi[0]); r[5] = (short)f2bf(hi[1]);
    r[6] = (short)f2bf(hi[2]); r[7] = (short)f2bf(hi[3]);
    return r;
}

#define GLDS16(gp, lp)                                                         \
    __builtin_amdgcn_global_load_lds(                                          \
        (const __attribute__((address_space(1))) void*)(gp),                   \
        (__attribute__((address_space(3))) void*)(lp), 16, 0, 0)

// Phase-B per-job LDS region: 3x16KB stage ring + 4x1280 u16 trans + bcs
#define JOB_LDS   61696
#define TRANS_OFF 49152
#define BCS_OFF   59392
// Phase-C (k2) layout
#define SMEM_BOFF 66560           // 64*1040
#define CHUNK_B   32768
#define SMEM_TOT  (66560 + 2 * 32768)   // 132096  (>= 2*JOB_LDS = 123392)

// ---------------------------------------------------------------------------
// mega: whole pipeline in ONE cooperative dispatch. 256 blocks x 512 thr.
//  A: Wc->Wc2[k][i][c] bf16 (masked cells untouched), bias dots, phiP pack.
//  B: wT[b][k][i] GEMM — 2 four-wave jobs/block, ring-3 staged Wc2 tiles,
//     exact counted vmcnt, operand-swap MFMA, full-line stores (v14 logic).
//  C: two chained GEMMs vs wT + bias + residual (k2 verbatim).
// __threadfence + grid.sync between phases (drains vmcnt -> counts exact).
// ---------------------------------------------------------------------------
__global__ __launch_bounds__(512, 1) void mega(
    const float* __restrict__ X, const float* __restrict__ phi,
    const float* __restrict__ Wc, const float* __restrict__ bc,
    unsigned short* __restrict__ Wc2, float* __restrict__ biasWS,
    unsigned short* __restrict__ phiP, unsigned short* __restrict__ wT,
    float* __restrict__ out)
{
    extern __shared__ char smem[];
    const int blk = blockIdx.x;
    const int tid = threadIdx.x;
    const int lane = tid & 63, wave = tid >> 6;

    // ================= Phase A =================
    {
#pragma unroll 4
        for (int it = 0; it < 32; ++it) {
            size_t g = ((((size_t)blk << 5) + it) << 9) + tid;   // < FF*16
            int p = (int)(g >> 4), u = (int)(g & 15);
            int i = p >> 9, k = p & 511;
            if ((i % 63) >= (k % 63)) {
                const float* src = Wc + ((size_t)p << 7) + (u << 3);
                s16x8 v = pack8(*(const f32x4*)src, *(const f32x4*)(src + 4));
                int up = u ^ (i & 7);
                *(s16x8*)&Wc2[(((size_t)((k << 9) | i)) << 7) + (up << 3)] = v;
            }
        }
        if (tid < 128) {                    // bias dots: 256*128 = 32768
            int g = (blk << 7) + tid;
            int k = g >> 6, b = g & 63;
            const f32x4* w4 = (const f32x4*)(Wc + (size_t)(FF_ + k) * C_);
            const f32x4* p4 = (const f32x4*)(phi + b * C_);
            float acc = bc[FF_ + k];
#pragma unroll
            for (int c = 0; c < 32; ++c) {
                f32x4 a = w4[c], q = p4[c];
                acc += a[0]*q[0] + a[1]*q[1] + a[2]*q[2] + a[3]*q[3];
            }
            biasWS[(b << 9) + k] = acc;
        }
        if (blk == 0) {                     // phiP pack: 1024 entries
#pragma unroll
            for (int j = 0; j < 2; ++j) {
                int e = (j << 9) + tid;
                int l2 = e & 63, mk = e >> 6;
                int m = mk >> 2, kk = mk & 3;
                int brow = l2 & 15, quad2 = l2 >> 4;
                const float* p = phi + ((m << 4) + brow) * C_ + kk * 32 + (quad2 << 3);
                s16x8 v = pack8(*(const f32x4*)p, *(const f32x4*)(p + 4));
                *(s16x8*)&phiP[e << 3] = v;
            }
        }
    }
    __threadfence();
    cg::this_grid().sync();

    // ================= Phase B =================
    {
        const int job  = (blk << 1) + (wave >> 2);   // 512 jobs
        const int w4   = wave & 3;
        const int tid4 = tid & 255;
        const int quad = lane >> 4;
        const int i0 = (job >> 6) << 6;
        const int k0 = (job & 63) << 3;

        char* jb = smem + (wave >> 2) * JOB_LDS;
        char* stgb = jb;                                      // 3 x 16384
        unsigned short* trans = (unsigned short*)(jb + TRANS_OFF);
        float* bcs = (float*)(jb + BCS_OFF);                  // [64][9]

        {
            int il = tid4 >> 2, kp = (tid4 & 3) << 1;
            const float* s = bc + (size_t)(i0 + il) * F_ + k0 + kp;
            bcs[il * 9 + kp]     = s[0];
            bcs[il * 9 + kp + 1] = s[1];
        }

        s16x8 bfr[4];
#pragma unroll
        for (int kk = 0; kk < 4; ++kk)
            bfr[kk] = *(const s16x8*)&phiP[((((w4 << 2) + kk) << 6) | lane) << 3];

        int dcell[4][4];
#pragma unroll
        for (int mt = 0; mt < 4; ++mt)
#pragma unroll
            for (int rr = 0; rr < 4; ++rr)
                dcell[mt][rr] = (i0 + mt * 16 + (quad << 2) + rr) % 63;
        int dmax[4];
#pragma unroll
        for (int mt = 0; mt < 4; ++mt) {
            int a = (i0 + mt * 16) % 63;
            dmax[mt] = (a + 15 >= 63) ? 62 : a + 15;
        }

        auto STAGE = [&](int t, int buf) {
            const int k = k0 + t;
#pragma unroll
            for (int j = 0; j < 4; ++j) {
                const int r0 = (w4 << 4) + (j << 2);          // 4 rows / inst
                const char* src = (const char*)Wc2
                                + (((size_t)((k << 9) + i0 + r0)) << 8)
                                + (lane << 4);                // per-lane source
                GLDS16(src, stgb + buf * 16384 + (r0 << 8));
            }
        };

        STAGE(0, 0); STAGE(1, 1);
        asm volatile("s_waitcnt lgkmcnt(0)" ::: "memory");
        __builtin_amdgcn_s_barrier();

        const int swz = lane & 7;

#pragma unroll
        for (int t = 0; t < 8; ++t) {
            if      (t == 0) asm volatile("s_waitcnt vmcnt(4)" ::: "memory");
            else if (t == 7) asm volatile("s_waitcnt vmcnt(2)" ::: "memory");
            else             asm volatile("s_waitcnt vmcnt(6)" ::: "memory");
            __builtin_amdgcn_s_barrier();

            const int dk = (k0 + t) % 63;
            const char* sb = stgb + (t % 3) * 16384;
            unsigned short* trw = trans + w4 * 1280;

#pragma unroll
            for (int mt = 0; mt < 4; ++mt) {
                const int tpos = ((lane & 15) * 160
                               + ((mt * 32 + (quad << 3)) ^ ((lane & 7) << 4))) >> 1;
                if (dmax[mt] >= dk) {
                    f32x4 acc = (f32x4){0.f, 0.f, 0.f, 0.f};
                    const int row = mt * 16 + (lane & 15);
                    const char* rowb = sb + (row << 8);
#pragma unroll
                    for (int kk = 0; kk < 4; ++kk) {
                        int u = ((kk << 2) + quad) ^ swz;
                        s16x8 afr = *(const s16x8*)(rowb + (u << 4));
                        acc = __builtin_amdgcn_mfma_f32_16x16x32_bf16(
                            afr, bfr[kk], acc, 0, 0, 0);
                    }
                    u16x4 v;
#pragma unroll
                    for (int rr = 0; rr < 4; ++rr) {
                        float bv = bcs[(mt * 16 + (quad << 2) + rr) * 9 + t];
                        v[rr] = (dcell[mt][rr] >= dk)
                              ? f2bf(acc[rr] + bv) : (unsigned short)0;
                    }
                    *(u16x4*)&trw[tpos] = v;
                } else {
                    *(u16x4*)&trw[tpos] = (u16x4){0, 0, 0, 0};
                }
            }

#pragma unroll
            for (int h = 0; h < 2; ++h) {
                int bl = (h << 3) + (lane >> 3), r = lane & 7;
                int rr2 = r ^ (bl & 7);
                s16x8 v = *(const s16x8*)&(trans + w4 * 1280)[bl * 80 + (rr2 << 3)];
                unsigned short* dst = wT
                    + (((size_t)((((w4 << 4) + bl) << 9) + k0 + t)) << 9)
                    + i0 + (r << 3);
                *(s16x8*)dst = v;
            }

            if (t < 6) STAGE(t + 2, (t + 2) % 3);
        }
    }
    __syncthreads();
    __threadfence();
    cg::this_grid().sync();

    // ================= Phase C (k2 verbatim) =================
    {
        unsigned short* A_lds = (unsigned short*)smem;

        const int sw = ((blk & 7) << 5) + (blk >> 3);   // XCD swizzle
        const int b  = sw >> 2;
        const int n0 = (sw & 3) << 6;
        const int wn = wave >> 2, wk = wave & 3;

        const float* Xb = X + (((size_t)(b * 256 + n0)) << 9);
        float*       Ob = out + (((size_t)(b * 256 + n0)) << 9);
        const unsigned short* wTb = wT + ((size_t)b << 18);

        float biasr[8];
#pragma unroll
        for (int nt = 0; nt < 8; ++nt)
            biasr[nt] = biasWS[(b << 9) + (wk << 7) + (nt << 4) + (lane & 15)];

        {
            const f32x4* X4 = (const f32x4*)Xb;
#pragma unroll
            for (int j = 0; j < 16; ++j) {
                int f = (j << 9) + tid;
                int row = f >> 7, c4 = f & 127;
                f32x4 v = X4[f];
                u16x4 h;
#pragma unroll
                for (int e = 0; e < 4; ++e) h[e] = f2bf(fmaxf(v[e], 0.f));
                *(u16x4*)&A_lds[row * 520 + (c4 << 2)] = h;
            }
        }

        const int srcslot = ((lane & 3) ^ ((lane >> 3) & 3)) << 3;

        f32x4 acc[2][8];

        for (int phase = 0; phase < 2; ++phase) {
#pragma unroll
            for (int mt = 0; mt < 2; ++mt)
#pragma unroll
                for (int nt = 0; nt < 8; ++nt) acc[mt][nt] = (f32x4){0.f, 0.f, 0.f, 0.f};

#pragma unroll
            for (int g = 0; g < 4; ++g) {
                int krow = (wave << 6) + (g << 4) + (lane >> 2);
                const unsigned short* src = wTb + ((size_t)krow << 9) + srcslot;
                char* lp = smem + SMEM_BOFF + (((wave << 6) + (g << 4)) << 6);
                GLDS16(src, lp);
            }
            asm volatile("s_waitcnt vmcnt(0)" ::: "memory");
            __syncthreads();

            for (int c = 0; c < 16; ++c) {
                const int cur = c & 1;
                if (c < 15) {
                    const int i0n = (c + 1) << 5;
#pragma unroll
                    for (int g = 0; g < 4; ++g) {
                        int krow = (wave << 6) + (g << 4) + (lane >> 2);
                        const unsigned short* src = wTb + ((size_t)krow << 9) + i0n + srcslot;
                        char* lp = smem + SMEM_BOFF + (cur ^ 1) * CHUNK_B
                                 + (((wave << 6) + (g << 4)) << 6);
                        GLDS16(src, lp);
                    }
                }
                const int i0c = c << 5;
                s16x8 afr[2];
#pragma unroll
                for (int mt = 0; mt < 2; ++mt) {
                    int n = (wn << 5) + (mt << 4) + (lane & 15);
                    afr[mt] = *(const s16x8*)&A_lds[n * 520 + i0c + ((lane >> 4) << 3)];
                }
                const unsigned short* Bb =
                    (const unsigned short*)(smem + SMEM_BOFF + cur * CHUNK_B);
#pragma unroll
                for (int nt = 0; nt < 8; ++nt) {
                    int k = (wk << 7) + (nt << 4) + (lane & 15);
                    int slot = (((lane >> 4) ^ ((k >> 1) & 3)) << 3);
                    s16x8 bfr = *(const s16x8*)&Bb[(k << 5) + slot];
#pragma unroll
                    for (int mt = 0; mt < 2; ++mt)
                        acc[mt][nt] = __builtin_amdgcn_mfma_f32_16x16x32_bf16(
                            afr[mt], bfr, acc[mt][nt], 0, 0, 0);
                }
                asm volatile("s_waitcnt vmcnt(0)" ::: "memory");
                __syncthreads();
            }

            if (phase == 0) {
#pragma unroll
                for (int mt = 0; mt < 2; ++mt)
#pragma unroll
                    for (int nt = 0; nt < 8; ++nt) {
                        int k = (wk << 7) + (nt << 4) + (lane & 15);
#pragma unroll
                        for (int r = 0; r < 4; ++r) {
                            int n = (wn << 5) + (mt << 4) + ((lane >> 4) << 2) + r;
                            A_lds[n * 520 + k] =
                                f2bf(fmaxf(acc[mt][nt][r] + biasr[nt], 0.f));
                        }
                    }
                __syncthreads();
            }
        }

#pragma unroll
        for (int mt = 0; mt < 2; ++mt)
#pragma unroll
            for (int nt = 0; nt < 8; ++nt) {
                int k = (wk << 7) + (nt << 4) + (lane & 15);
#pragma unroll
                for (int r = 0; r < 4; ++r) {
                    int n = (wn << 5) + (mt << 4) + ((lane >> 4) << 2) + r;
                    size_t off = ((size_t)n << 9) + k;
                    Ob[off] = Xb[off] + acc[mt][nt][r] + biasr[nt];
                }
            }
    }
}

extern "C" void kernel_launch(void* const* d_in, const int* in_sizes, int n_in,
                              void* d_out, int out_size, void* d_ws, size_t ws_size,
                              hipStream_t stream) {
    const float* inputs = (const float*)d_in[0];
    const float* phi    = (const float*)d_in[1];
    const float* Wc     = (const float*)d_in[2];
    const float* bc     = (const float*)d_in[3];
    float* out = (float*)d_out;

    unsigned short* wT = (unsigned short*)d_ws;                          // 32 MiB
    float* biasWS = (float*)((char*)d_ws + (size_t)64 * 512 * 512 * 2);  // 128 KiB
    unsigned short* phiP =
        (unsigned short*)((char*)d_ws + (size_t)64 * 512 * 512 * 2 + 64 * 512 * 4);
    unsigned short* Wc2 =
        (unsigned short*)((char*)d_ws + ((size_t)64 << 20));             // 64 MiB @64M

    hipFuncSetAttribute((const void*)mega,
                        hipFuncAttributeMaxDynamicSharedMemorySize, SMEM_TOT);

    void* args[] = { (void*)&inputs, (void*)&phi, (void*)&Wc, (void*)&bc,
                     (void*)&Wc2, (void*)&biasWS, (void*)&phiP, (void*)&wT,
                     (void*)&out };
    hipLaunchCooperativeKernel((const void*)mega, dim3(256), dim3(512),
                               args, SMEM_TOT, stream);
}

// Round 14
// 71.837 us; speedup vs baseline: 3.5937x; 3.5937x over previous
//
#include <hip/hip_runtime.h>
#include <hip/hip_bf16.h>

#define F_   512
#define FF_  (512 * 512)
#define C_   128

typedef __attribute__((ext_vector_type(4))) float f32x4;
typedef __attribute__((ext_vector_type(8))) short s16x8;
typedef __attribute__((ext_vector_type(4))) unsigned short u16x4;

__device__ __forceinline__ unsigned short f2bf(float f) {
    union { __hip_bfloat16 h; unsigned short u; } c;
    c.h = __float2bfloat16(f);
    return c.u;
}

__device__ __forceinline__ s16x8 pack8(f32x4 lo, f32x4 hi) {
    s16x8 r;
    r[0] = (short)f2bf(lo[0]); r[1] = (short)f2bf(lo[1]);
    r[2] = (short)f2bf(lo[2]); r[3] = (short)f2bf(lo[3]);
    r[4] = (short)f2bf(hi[0]); r[5] = (short)f2bf(hi[1]);
    r[6] = (short)f2bf(hi[2]); r[7] = (short)f2bf(hi[3]);
    return r;
}

#define GLDS16(gp, lp)                                                         \
    __builtin_amdgcn_global_load_lds(                                          \
        (const __attribute__((address_space(1))) void*)(gp),                   \
        (__attribute__((address_space(3))) void*)(lp), 16, 0, 0)

// ---------------------------------------------------------------------------
// Kernel 0: pre-pack phi -> per-(bt,kk,lane) bf16 MFMA B-fragments.
// frag elem: lane l holds phi[bt*16 + (l&15)][kk*32 + (l>>4)*8 .. +8].
// ---------------------------------------------------------------------------
__global__ __launch_bounds__(256) void k0_prepack(
    const float* __restrict__ phi, unsigned short* __restrict__ phiP)
{
    const int t = threadIdx.x;
#pragma unroll
    for (int j = 0; j < 4; ++j) {
        int e = (j << 8) + t;               // 0..1023
        int lane = e & 63, mk = e >> 6;
        int m = mk >> 2, kk = mk & 3;
        int brow = lane & 15, quad = lane >> 4;
        const float* p = phi + ((m << 4) + brow) * C_ + kk * 32 + (quad << 3);
        s16x8 v = pack8(*(const f32x4*)p, *(const f32x4*)(p + 4));
        *(s16x8*)&phiP[e << 3] = v;
    }
}

// ---------------------------------------------------------------------------
// Kernel 1 v9: operand-swapped, wave-private, BARRIER-FREE.
// D = A(Wc rows: M=16 i-cells, one k) x B(phi: N=16 b) -> lane's 4 regs are
// 4 CONSECUTIVE i for fixed (b,k): pack ushort4, store straight to
// wT[b][k][i]. No LDS transpose, no barriers. Per wave: own (16i x 8k)
// region, 8 iters; per iter: 8 contiguous glds (dbuf, uniform counted
// vmcnt), 8 swizzled ds_read_b128, 16 MFMA, 4 x 8B-per-lane stores.
// Fully-masked k: skip compute, stage dup rows (L1 hit, vmcnt uniform).
// Blocks 0..511 compute (2/CU); 512..639 bias rows.
// ---------------------------------------------------------------------------
__global__ __launch_bounds__(256, 2) void k1_params(
    const unsigned short* __restrict__ phiP, const float* __restrict__ Wc,
    const float* __restrict__ bc, unsigned short* __restrict__ wT,
    float* __restrict__ biasWS, const float* __restrict__ phi)
{
    const int blk = blockIdx.x;
    const int tid = threadIdx.x;

    if (blk >= 512) {                       // ---- bias part ----
        int g = ((blk - 512) << 8) + tid;   // 0..32767
        int k = g >> 6, b = g & 63;
        const f32x4* w4 = (const f32x4*)(Wc + (size_t)(FF_ + k) * C_);
        const f32x4* p4 = (const f32x4*)(phi + b * C_);
        float acc = bc[FF_ + k];
#pragma unroll
        for (int c = 0; c < 32; ++c) {
            f32x4 a = w4[c], q = p4[c];
            acc += a[0]*q[0] + a[1]*q[1] + a[2]*q[2] + a[3]*q[3];
        }
        biasWS[(b << 9) + k] = acc;
        return;
    }

    __shared__ __align__(16) char stg[4][2][8192];   // wave-private dbuf, 64 KB

    const int lane = tid & 63, wave = tid >> 6, quad = lane >> 4;
    const int w  = (blk << 2) + wave;       // global wave id 0..2047
    const int i0 = (w & 31) << 4;           // 32 i-tiles of 16
    const int k0 = (w >> 5) << 3;           // 64 k-octets

    // ---- B-fragments (phi) from phiP: 16 contiguous 1KB loads (64 VGPR)
    s16x8 bfrP[4][4];
#pragma unroll
    for (int mk = 0; mk < 16; ++mk)
        bfrP[mk >> 2][mk & 3] = *(const s16x8*)&phiP[((mk << 6) + lane) << 3];

    // ---- bias regs: bias[rr][ct] = bc[(i0+quad*4+rr)*512 + k0+ct]
    f32x4 biasv[4][2];
#pragma unroll
    for (int rr = 0; rr < 4; ++rr) {
        const float* p = bc + (i0 + (quad << 2) + rr) * F_ + k0;
        biasv[rr][0] = *(const f32x4*)p;
        biasv[rr][1] = *(const f32x4*)(p + 4);
    }

    // ---- keep bits: bit(ct*4+rr) = d_i >= d_k ; per-ct wave-uniform skip
    unsigned keepm = 0;
    {
#pragma unroll
        for (int ct = 0; ct < 8; ++ct) {
            int dk = (k0 + ct) % 63;
#pragma unroll
            for (int rr = 0; rr < 4; ++rr) {
                int di = (i0 + (quad << 2) + rr) % 63;
                if (di >= dk) keepm |= 1u << ((ct << 2) + rr);
            }
        }
    }
    int maxd = i0 % 63 + 15; maxd = maxd > 62 ? 62 : maxd;
    unsigned skipm = 0;
#pragma unroll
    for (int ct = 0; ct < 8; ++ct)
        if (((k0 + ct) % 63) > maxd) skipm |= 1u << ct;

    // ---- staging: 8 glds/tile; glds j covers rows 2j,2j+1 (row = i-local)
    const int r2 = lane >> 5, s = lane & 31;
    char* const stw0 = stg[wave][0];
    char* const stw1 = stg[wave][1];

    auto STAGE = [&](int ct, char* dst) {
        const bool sk = (skipm >> ct) & 1;
        const int  k  = k0 + ct;
#pragma unroll
        for (int j = 0; j < 8; ++j) {
            int row = (j << 1) + r2;
            int isrc = sk ? i0 : (i0 + row);          // dup row when skipped
            const char* src = (const char*)(Wc + ((size_t)(isrc * F_ + k)) * C_)
                            + ((s << 4) ^ ((row & 7) << 6));
            GLDS16(src, dst + (row << 9) + ((s << 4) ^ ((row & 7) << 6)));
        }
    };
    // NOTE dest above: linear per lane = j*1024 + r2*512 + s*16 == row*512+s*16
    // but we wrote swizzled form; glds dest MUST be base+lane*16. Fix: dest
    // linear, source carries the swizzle (rule 21). See corrected call below.

    // drain prologue loads so counted vmcnt is exact
    asm volatile("s_waitcnt vmcnt(0)" ::: "memory");

    // corrected STAGE (linear dest):
    auto STAGE2 = [&](int ct, char* dst) {
        const bool sk = (skipm >> ct) & 1;
        const int  k  = k0 + ct;
#pragma unroll
        for (int j = 0; j < 8; ++j) {
            int row = (j << 1) + r2;
            int isrc = sk ? i0 : (i0 + row);
            const char* src = (const char*)(Wc + ((size_t)(isrc * F_ + k)) * C_)
                            + ((s << 4) ^ ((row & 7) << 6));
            GLDS16(src, dst + (j << 10));   // + lane*16 implicit -> row*512+s*16
        }
    };
    (void)STAGE;

    STAGE2(0, stw0);

#pragma unroll
    for (int ct = 0; ct < 8; ++ct) {
        char* bufc = (ct & 1) ? stw1 : stw0;
        if (ct < 7) STAGE2(ct + 1, (ct & 1) ? stw0 : stw1);

        if (ct == 0)      asm volatile("s_waitcnt vmcnt(8)"  ::: "memory");
        else if (ct < 7)  asm volatile("s_waitcnt vmcnt(12)" ::: "memory");
        else              asm volatile("s_waitcnt vmcnt(4)"  ::: "memory");
        __builtin_amdgcn_sched_barrier(0);

        f32x4 acc[4];
#pragma unroll
        for (int bt = 0; bt < 4; ++bt) acc[bt] = (f32x4){0.f, 0.f, 0.f, 0.f};

        const bool sk = (skipm >> ct) & 1;
        if (!sk) {
            const int rowB = (lane & 15) << 9;      // row*512
            const int swz  = (lane & 7) << 6;
#pragma unroll
            for (int kk = 0; kk < 4; ++kk) {
                int x0 = ((kk << 7) + (quad << 5)) ^ swz;
                int x1 = ((kk << 7) + (quad << 5) + 16) ^ swz;
                f32x4 lo = *(const f32x4*)(bufc + rowB + x0);
                f32x4 hi = *(const f32x4*)(bufc + rowB + x1);
                s16x8 aW = pack8(lo, hi);
#pragma unroll
                for (int bt = 0; bt < 4; ++bt)
                    acc[bt] = __builtin_amdgcn_mfma_f32_16x16x32_bf16(
                        aW, bfrP[bt][kk], acc[bt], 0, 0, 0);
            }
        }

        // ---- direct store: lane's 4 regs = i0+quad*4+rr for (b, k0+ct)
        const int k = k0 + ct;
#pragma unroll
        for (int bt = 0; bt < 4; ++bt) {
            u16x4 v;
#pragma unroll
            for (int rr = 0; rr < 4; ++rr) {
                bool kp = (!sk) && ((keepm >> ((ct << 2) + rr)) & 1);
                float bv = (ct < 4) ? biasv[rr][0][ct] : biasv[rr][1][ct - 4];
                v[rr] = kp ? f2bf(acc[bt][rr] + bv) : (unsigned short)0;
            }
            int b = (bt << 4) + (lane & 15);
            *(u16x4*)&wT[(((size_t)((b << 9) + k)) << 9) + i0 + (quad << 2)] = v;
        }
    }
}

// ---------------------------------------------------------------------------
// Kernel 2 (unchanged): two chained GEMMs vs wT + bias, residual epilogue.
// ---------------------------------------------------------------------------
#define SMEM_BOFF 66560           // 64*1040
#define CHUNK_B   32768
#define SMEM_TOT  (66560 + 2 * 32768)   // 132096

__global__ __launch_bounds__(512) void k2_apply(
    const float* __restrict__ X, const unsigned short* __restrict__ wT,
    const float* __restrict__ biasWS, float* __restrict__ out)
{
    extern __shared__ char smem[];
    unsigned short* A_lds = (unsigned short*)smem;

    const int blk = blockIdx.x;
    const int sw  = ((blk & 7) << 5) + (blk >> 3);   // XCD swizzle
    const int b   = sw >> 2;
    const int n0  = (sw & 3) << 6;

    const int tid = threadIdx.x, lane = tid & 63, wave = tid >> 6;
    const int wn = wave >> 2, wk = wave & 3;

    const float* Xb = X + (((size_t)(b * 256 + n0)) << 9);
    float*       Ob = out + (((size_t)(b * 256 + n0)) << 9);
    const unsigned short* wTb = wT + ((size_t)b << 18);

    float biasr[8];
#pragma unroll
    for (int nt = 0; nt < 8; ++nt)
        biasr[nt] = biasWS[(b << 9) + (wk << 7) + (nt << 4) + (lane & 15)];

    {
        const f32x4* X4 = (const f32x4*)Xb;
#pragma unroll
        for (int j = 0; j < 16; ++j) {
            int f = (j << 9) + tid;
            int row = f >> 7, c4 = f & 127;
            f32x4 v = X4[f];
            u16x4 h;
#pragma unroll
            for (int e = 0; e < 4; ++e) h[e] = f2bf(fmaxf(v[e], 0.f));
            *(u16x4*)&A_lds[row * 520 + (c4 << 2)] = h;
        }
    }

    const int srcslot = ((lane & 3) ^ ((lane >> 3) & 3)) << 3;

    f32x4 acc[2][8];

    for (int phase = 0; phase < 2; ++phase) {
#pragma unroll
        for (int mt = 0; mt < 2; ++mt)
#pragma unroll
            for (int nt = 0; nt < 8; ++nt) acc[mt][nt] = (f32x4){0.f, 0.f, 0.f, 0.f};

#pragma unroll
        for (int g = 0; g < 4; ++g) {
            int krow = (wave << 6) + (g << 4) + (lane >> 2);
            const unsigned short* src = wTb + ((size_t)krow << 9) + srcslot;
            char* lp = smem + SMEM_BOFF + (((wave << 6) + (g << 4)) << 6);
            GLDS16(src, lp);
        }
        asm volatile("s_waitcnt vmcnt(0)" ::: "memory");
        __syncthreads();

        for (int c = 0; c < 16; ++c) {
            const int cur = c & 1;
            if (c < 15) {
                const int i0n = (c + 1) << 5;
#pragma unroll
                for (int g = 0; g < 4; ++g) {
                    int krow = (wave << 6) + (g << 4) + (lane >> 2);
                    const unsigned short* src = wTb + ((size_t)krow << 9) + i0n + srcslot;
                    char* lp = smem + SMEM_BOFF + (cur ^ 1) * CHUNK_B
                             + (((wave << 6) + (g << 4)) << 6);
                    GLDS16(src, lp);
                }
            }
            const int i0c = c << 5;
            s16x8 afr[2];
#pragma unroll
            for (int mt = 0; mt < 2; ++mt) {
                int n = (wn << 5) + (mt << 4) + (lane & 15);
                afr[mt] = *(const s16x8*)&A_lds[n * 520 + i0c + ((lane >> 4) << 3)];
            }
            const unsigned short* Bb =
                (const unsigned short*)(smem + SMEM_BOFF + cur * CHUNK_B);
#pragma unroll
            for (int nt = 0; nt < 8; ++nt) {
                int k = (wk << 7) + (nt << 4) + (lane & 15);
                int slot = (((lane >> 4) ^ ((k >> 1) & 3)) << 3);
                s16x8 bfr = *(const s16x8*)&Bb[(k << 5) + slot];
#pragma unroll
                for (int mt = 0; mt < 2; ++mt)
                    acc[mt][nt] = __builtin_amdgcn_mfma_f32_16x16x32_bf16(
                        afr[mt], bfr, acc[mt][nt], 0, 0, 0);
            }
            asm volatile("s_waitcnt vmcnt(0)" ::: "memory");
            __syncthreads();
        }

        if (phase == 0) {
#pragma unroll
            for (int mt = 0; mt < 2; ++mt)
#pragma unroll
                for (int nt = 0; nt < 8; ++nt) {
                    int k = (wk << 7) + (nt << 4) + (lane & 15);
#pragma unroll
                    for (int r = 0; r < 4; ++r) {
                        int n = (wn << 5) + (mt << 4) + ((lane >> 4) << 2) + r;
                        A_lds[n * 520 + k] =
                            f2bf(fmaxf(acc[mt][nt][r] + biasr[nt], 0.f));
                    }
                }
            __syncthreads();
        }
    }

#pragma unroll
    for (int mt = 0; mt < 2; ++mt)
#pragma unroll
        for (int nt = 0; nt < 8; ++nt) {
            int k = (wk << 7) + (nt << 4) + (lane & 15);
#pragma unroll
            for (int r = 0; r < 4; ++r) {
                int n = (wn << 5) + (mt << 4) + ((lane >> 4) << 2) + r;
                size_t off = ((size_t)n << 9) + k;
                Ob[off] = Xb[off] + acc[mt][nt][r] + biasr[nt];
            }
        }
}

extern "C" void kernel_launch(void* const* d_in, const int* in_sizes, int n_in,
                              void* d_out, int out_size, void* d_ws, size_t ws_size,
                              hipStream_t stream) {
    const float* inputs = (const float*)d_in[0];
    const float* phi    = (const float*)d_in[1];
    const float* Wc     = (const float*)d_in[2];
    const float* bc     = (const float*)d_in[3];
    float* out = (float*)d_out;

    unsigned short* wT = (unsigned short*)d_ws;                          // 32 MiB
    float* biasWS = (float*)((char*)d_ws + (size_t)64 * 512 * 512 * 2);  // 128 KiB
    unsigned short* phiP =
        (unsigned short*)((char*)d_ws + (size_t)64 * 512 * 512 * 2 + 64 * 512 * 4);

    hipLaunchKernelGGL(k0_prepack, dim3(1), dim3(256), 0, stream, phi, phiP);

    hipLaunchKernelGGL(k1_params, dim3(640), dim3(256), 0, stream,
                       phiP, Wc, bc, wT, biasWS, phi);

    hipFuncSetAttribute((const void*)k2_apply,
                        hipFuncAttributeMaxDynamicSharedMemorySize, SMEM_TOT);
    hipLaunchKernelGGL(k2_apply, dim3(256), dim3(512), SMEM_TOT, stream,
                       inputs, wT, biasWS, out);
}